// Round 1
// baseline (313.154 us; speedup 1.0000x reference)
//
#include <hip/hip_runtime.h>

// CSTR gated-estimator trajectory cost — 1 lane per sample (latency-bound regime).
// B=8192 samples, T=2048 sequential RK4 steps, N=2 states.
//
// Rationale (rocprof): 0% MFMA, 15.8% VALUBusy, 2.8% occupancy, 5% HBM ->
// wall clock = T x per-step dependent-chain latency. Previous 2-lane kernel had
// 3 DPP swaps + a 6-deep serial fma chain + exp + rcp on the chain (~188 cyc/step).
// This version keeps the whole sample in one lane:
//   - phi evaluated as a balanced depth-5 tree over (x1,x2,xh1,xh2), packed fp32
//     (float2 ext-vector -> v_pk_fma_f32), coefficients pre-scaled by -log2(e);
//   - constant Mo folded multiplicatively: d = rcp(fma(exp(-c0), exp2(ph), 1));
//   - control folded into per-state fma: x' = pf + d*kdx, xh' = xh + d*dx, with
//     pf = pre + Hs*K.xh and kdx = Hs*K.(x-xh) computed off the d-chain;
//   - cost via {Sum x1^2, Sum x2^2, Sum x1x2} so Sum (K.x)^2 is reconstructed once.
// RK4 collapsed analytically (affine plant):
//   x1' = 0.98 x1 + 0.01 x2 + 0.01 u + H^2/2 + w1
//   x2' = 0.98 x2 + 0.01 x1 + 0.01 u - H^2   + w2

#define T_STEPS 2048
#define BATCH   8192

typedef float v2f __attribute__((ext_vector_type(2)));

__device__ __forceinline__ v2f mk2(float a, float b) { v2f r; r.x = a; r.y = b; return r; }

__global__ __launch_bounds__(64, 1) void cstr_kernel(
    const float* __restrict__ w,   // (B, 2, T)
    const float* __restrict__ K,   // (1, 2)
    const float* __restrict__ L,   // (4, 4)
    const float* __restrict__ M,   // (1, 4)
    const float* __restrict__ Mo,  // (1, 1)
    float* __restrict__ out)       // (B,)
{
    const int s = blockIdx.x * 64 + (int)threadIdx.x;

    constexpr float Hs = 0.01f;
    constexpr float Ad = 1.0f - 2.0f * Hs;          // 0.98
    constexpr float Rc = 0.1f;
    constexpr float SC = -1.44269504088896340736f;  // -log2(e)

    const float k1 = K[0], k2 = K[1];

    // folded symmetric quadratic coefficients (s_ij = L_ij + L_ji, i<j), *SC
    const float s11 = L[0] * SC;
    const float s12 = (L[1] + L[4]) * SC;
    const float s13 = (L[2] + L[8]) * SC;
    const float s14 = (L[3] + L[12]) * SC;
    const float s22 = L[5] * SC;
    const float s23 = (L[6] + L[9]) * SC;
    const float s24 = (L[7] + L[13]) * SC;
    const float s33 = L[10] * SC;
    const float s34 = (L[11] + L[14]) * SC;
    const float s44 = L[15] * SC;

    const v2f S11_22 = mk2(s11, s22);
    const v2f S12_0  = mk2(s12, 0.0f);
    const v2f S13_23 = mk2(s13, s23);
    const v2f S14_24 = mk2(s14, s24);
    const v2f S33_44 = mk2(s33, s44);
    const v2f S34_0  = mk2(s34, 0.0f);
    const v2f M12    = mk2(M[0] * SC, M[1] * SC);
    const v2f M34    = mk2(M[2] * SC, M[3] * SC);
    const float kc   = __builtin_amdgcn_exp2f(Mo[0] * SC);  // exp(-c0)

    const v2f HK  = mk2(Hs * k1, Hs * k2);
    const v2f C12 = mk2(0.5f * Hs * Hs, -Hs * Hs);

    // ---- state ----
    v2f x  = mk2(1.0f, 0.0f);     // x0 = (1, 0)
    v2f xh = x;
    v2f acc2  = mk2(0.0f, 0.0f);  // {sum x1^2, sum x2^2}
    float accXY = 0.0f;           // sum x1*x2
    float accD  = 0.0f;           // sum delta

    auto step = [&](float w1, float w2, bool first, bool cost) {
        // ---- early work, off the d-chain (overlaps previous exp/rcp) ----
        v2f   dx  = x - xh;
        v2f   tk  = HK * dx;
        float kdx = tk.x + tk.y;               // Hs*K.(x - xh)
        v2f   th  = HK * xh;
        float kxh = th.x + th.y;               // Hs*K.xh (pre-update)
        v2f   wc  = mk2(w1, w2) + C12;
        v2f   pre = Ad * x + (Hs * mk2(x.y, x.x) + wc);
        v2f   pf  = pre + kxh;

        float d;
        if (first) {
            d = 1.0f;                           // i==0: gate forced open
        } else {
            // phi tree: g1 = s11 x1 + s12 x2 + s13 h1 + s14 h2 + m1
            //           g2 = s22 x2 +          s23 h1 + s24 h2 + m2
            //           g3 = s33 h1 + s34 h2 + m3 ; g4 = s44 h2 + m4
            //           ph = x1 g1 + x2 g2 + h1 g3 + h2 g4   (c0 folded into kc)
            v2f a   = S11_22 * x + M12;
            a       = S12_0 * x.y + a;
            v2f b   = S13_23 * xh.x;
            b       = S14_24 * xh.y + b;
            v2f g12 = a + b;
            v2f c   = S33_44 * xh + M34;
            v2f g34 = S34_0 * xh.y + c;
            v2f Q   = xh * g34 + x * g12;
            float ph = Q.x + Q.y;
            float E  = __builtin_amdgcn_exp2f(ph);          // exp(-(quad+lin))
            d = __builtin_amdgcn_rcpf(fmaf(kc, E, 1.0f));   // sigmoid(phi)
        }
        if (cost) {                             // stage cost uses PRE-update x
            acc2  = x * x + acc2;
            accXY = fmaf(x.x, x.y, accXY);
            accD += d;
        }
        // u = K.xh_new = K.xh + d*K.dx  ->  Hs*u = kxh + d*kdx (kxh already in pf)
        xh = d * dx + xh;
        x  = d * kdx + pf;
    };

    auto chunk = [&](const float4* b0, const float4* b1, bool first, bool lastc) {
        #pragma unroll
        for (int q = 0; q < 4; ++q) {
            float4 a = b0[q];
            float4 b = b1[q];
            step(a.x, b.x, first && (q == 0), true);
            step(a.y, b.y, false, true);
            step(a.z, b.z, false, true);
            step(a.w, b.w, false, !(lastc && (q == 3)));  // t=T-1: no stage cost
        }
    };

    // two per-lane streams: w row 0 and row 1 of this sample
    const float4* r0 = reinterpret_cast<const float4*>(w + (size_t)s * 2 * T_STEPS);
    const float4* r1 = reinterpret_cast<const float4*>(w + (size_t)s * 2 * T_STEPS + T_STEPS);

    // 16-step chunks (4 float4 per row), double-buffered: prefetch ~16 steps ahead
    float4 A0[4], A1[4], B0[4], B1[4];
    #pragma unroll
    for (int q = 0; q < 4; ++q) { A0[q] = r0[q];     A1[q] = r1[q]; }
    #pragma unroll
    for (int q = 0; q < 4; ++q) { B0[q] = r0[4 + q]; B1[q] = r1[4 + q]; }

    chunk(A0, A1, true, false);                        // chunk 0 (step 0 special)

    for (int i = 0; i < 63; ++i) {                     // chunks 1..126
        const float4* p0 = r0 + (size_t)(2 + 2 * i) * 4;
        const float4* p1 = r1 + (size_t)(2 + 2 * i) * 4;
        #pragma unroll
        for (int q = 0; q < 4; ++q) { A0[q] = p0[q]; A1[q] = p1[q]; }
        chunk(B0, B1, false, false);                   // process chunk 1+2i
        const float4* q0 = r0 + (size_t)(3 + 2 * i) * 4;
        const float4* q1 = r1 + (size_t)(3 + 2 * i) * 4;
        #pragma unroll
        for (int q = 0; q < 4; ++q) { B0[q] = q0[q]; B1[q] = q1[q]; }
        chunk(A0, A1, false, false);                   // process chunk 2+2i
    }
    chunk(B0, B1, false, true);                        // chunk 127 (last: no cost)

    // Sum us^2 = k1^2*Sx1^2 + k2^2*Sx2^2 + 2 k1 k2*Sx1x2  (before terminal fold)
    float sum_us2 = fmaf(k1 * k1, acc2.x,
                    fmaf(k2 * k2, acc2.y, 2.0f * k1 * k2 * accXY));
    // terminal cost 10*(x1^2 + x2^2)
    acc2 = 10.0f * (x * x) + acc2;
    float J = acc2.x + acc2.y + Rc * sum_us2 + accD;
    out[s] = J;
}

extern "C" void kernel_launch(void* const* d_in, const int* in_sizes, int n_in,
                              void* d_out, int out_size, void* d_ws, size_t ws_size,
                              hipStream_t stream) {
    const float* w  = (const float*)d_in[0];
    const float* K  = (const float*)d_in[1];
    const float* L  = (const float*)d_in[2];
    const float* M  = (const float*)d_in[3];
    const float* Mo = (const float*)d_in[4];
    float* out = (float*)d_out;

    // 8192 samples, 1 lane each = 128 blocks of 64 (1 wave/block, 1 wave/CU)
    hipLaunchKernelGGL(cstr_kernel, dim3(BATCH / 64), dim3(64), 0, stream,
                       w, K, L, M, Mo, out);
}